// Round 1
// baseline (112.440 us; speedup 1.0000x reference)
//
#include <hip/hip_runtime.h>

#define HALF   4096
#define NROWS  8192
#define DDIM   128
#define NSLICES 8
#define COLS_PER_SLICE (NROWS / NSLICES)   // 1024
#define LDS_STRIDE 272                      // 256B row + 16B pad (uniform bank spread)

typedef _Float16 v8h __attribute__((ext_vector_type(8)));
typedef float    v4f __attribute__((ext_vector_type(4)));

#if __has_builtin(__builtin_amdgcn_exp2f)
#define EXP2F(x) __builtin_amdgcn_exp2f(x)
#else
#define EXP2F(x) exp2f(x)
#endif
#if __has_builtin(__builtin_amdgcn_logf)
#define LOG2F(x) __builtin_amdgcn_logf(x)
#else
#define LOG2F(x) __log2f(x)
#endif

// ---------------- Kernel 1: row-normalize concat(z_i, z_j) -> fp16 ----------------
// one wave per row; lane handles 2 columns
__global__ __launch_bounds__(256) void nt_normalize(
        const float* __restrict__ z_i, const float* __restrict__ z_j,
        _Float16* __restrict__ zn) {
    int tid  = threadIdx.x;
    int lane = tid & 63;
    int row  = blockIdx.x * 4 + (tid >> 6);
    const float* src = (row < HALF) ? (z_i + (size_t)row * DDIM)
                                    : (z_j + (size_t)(row - HALF) * DDIM);
    float2 v = *(const float2*)(src + lane * 2);
    float ss = v.x * v.x + v.y * v.y;
    #pragma unroll
    for (int off = 32; off >= 1; off >>= 1)
        ss += __shfl_xor(ss, off, 64);
    float inv = 1.0f / fmaxf(sqrtf(ss), 1e-8f);
    _Float16 a = (_Float16)(v.x * inv);
    _Float16 b = (_Float16)(v.y * inv);
    _Float16* dst = zn + (size_t)row * DDIM + lane * 2;
    dst[0] = a; dst[1] = b;
}

// ---------------- Kernel 2: fused Gram (zn @ zn^T) + shifted sum-exp ----------------
// grid: 128 row-groups x 8 column slices. block: 256 thr = 4 waves x 16 rows.
// Per iteration: stage 64 columns (64x128 f16) into LDS; each wave does
// 4 col-subtiles x 4 K-steps of mfma_f32_16x16x32_f16; accumulate exp(2g-2),
// masking the partner column (reference's excluded pair).
__global__ __launch_bounds__(256) void nt_gram_lse(
        const _Float16* __restrict__ zn, float* __restrict__ S_part) {
    __shared__ unsigned char lds[64 * LDS_STRIDE];

    int tid  = threadIdx.x;
    int lane = tid & 63;
    int w    = tid >> 6;       // wave 0..3
    int quad = lane >> 4;      // 0..3
    int cl   = lane & 15;      // 0..15

    int rg    = blockIdx.x >> 3;        // 0..127
    int slice = blockIdx.x & 7;         // 0..7
    int r0    = rg * 64;
    int c0    = slice * COLS_PER_SLICE;

    // A fragments for this wave's 16 rows (kept in registers for whole kernel)
    // A-operand layout: lane holds A[m = lane&15][k = quad*8 + j], 16B contiguous
    int arow = r0 + w * 16 + cl;
    v8h a[4];
    #pragma unroll
    for (int t = 0; t < 4; ++t)
        a[t] = *(const v8h*)(zn + (size_t)arow * DDIM + t * 32 + quad * 8);

    // Output rows per C/D layout: row = quad*4 + reg, col = lane&15
    int   orow[4], partner[4];
    float sums[4] = {0.f, 0.f, 0.f, 0.f};
    #pragma unroll
    for (int r = 0; r < 4; ++r) {
        orow[r]    = r0 + w * 16 + quad * 4 + r;
        partner[r] = (orow[r] + HALF) & (NROWS - 1);
    }

    const uint4* gb = (const uint4*)zn;   // 1 uint4 = 8 f16 elements
    const float C = 2.8853900817779268f;  // 2/ln2 ; exp(2g-2) = 2^(C*g - C)

    for (int it = 0; it < COLS_PER_SLICE / 64; ++it) {
        int ct = c0 + it * 64;
        // stage 64 columns x 128 k (16 KB) into LDS, padded rows
        #pragma unroll
        for (int i = 0; i < 4; ++i) {
            uint4 v = gb[ct * 16 + i * 256 + tid];
            *(uint4*)&lds[(size_t)((tid >> 4) + i * 16) * LDS_STRIDE + (tid & 15) * 16] = v;
        }
        __syncthreads();

        #pragma unroll
        for (int sub = 0; sub < 4; ++sub) {
            v4f acc = {0.f, 0.f, 0.f, 0.f};
            #pragma unroll
            for (int t = 0; t < 4; ++t) {
                v8h b = *(const v8h*)&lds[(size_t)(sub * 16 + cl) * LDS_STRIDE + t * 64 + quad * 16];
                acc = __builtin_amdgcn_mfma_f32_16x16x32_f16(a[t], b, acc, 0, 0, 0);
            }
            int col = ct + sub * 16 + cl;
            #pragma unroll
            for (int r = 0; r < 4; ++r) {
                float e = EXP2F(fmaf(acc[r], C, -C));
                sums[r] += (col == partner[r]) ? 0.f : e;
            }
        }
        __syncthreads();
    }

    // reduce across the 16 column-lanes of each quad group
    #pragma unroll
    for (int r = 0; r < 4; ++r) {
        float s = sums[r];
        #pragma unroll
        for (int off = 1; off < 16; off <<= 1)
            s += __shfl_xor(s, off, 64);
        if (cl == 0)
            S_part[(size_t)slice * NROWS + orow[r]] = s;
    }
}

// ---------------- Kernel 3: loss = mean_r log(sum_slices S_part) ----------------
__global__ __launch_bounds__(256) void nt_finalize(
        const float* __restrict__ S_part, float* __restrict__ out) {
    __shared__ float red[4];
    int tid = threadIdx.x;
    float acc = 0.f;
    for (int r = tid; r < NROWS; r += 256) {
        float s = 0.f;
        #pragma unroll
        for (int sl = 0; sl < NSLICES; ++sl)
            s += S_part[(size_t)sl * NROWS + r];
        acc += LOG2F(s);
    }
    #pragma unroll
    for (int off = 32; off >= 1; off >>= 1)
        acc += __shfl_xor(acc, off, 64);
    if ((tid & 63) == 0) red[tid >> 6] = acc;
    __syncthreads();
    if (tid == 0) {
        float t = red[0] + red[1] + red[2] + red[3];
        out[0] = t * (0.69314718055994531f / (float)NROWS);
    }
}

extern "C" void kernel_launch(void* const* d_in, const int* in_sizes, int n_in,
                              void* d_out, int out_size, void* d_ws, size_t ws_size,
                              hipStream_t stream) {
    const float* z_i = (const float*)d_in[0];
    const float* z_j = (const float*)d_in[1];
    _Float16* zn     = (_Float16*)d_ws;                                   // 2 MB
    float*    S_part = (float*)((char*)d_ws + (size_t)NROWS * DDIM * 2);  // 8*8192 fp32
    float*    out    = (float*)d_out;

    nt_normalize<<<dim3(NROWS / 4), dim3(256), 0, stream>>>(z_i, z_j, zn);
    nt_gram_lse<<<dim3(128 * NSLICES), dim3(256), 0, stream>>>(zn, S_part);
    nt_finalize<<<dim3(1), dim3(256), 0, stream>>>(S_part, out);
}

// Round 2
// 108.155 us; speedup vs baseline: 1.0396x; 1.0396x over previous
//
#include <hip/hip_runtime.h>

#define HALF   4096
#define NROWS  8192
#define DDIM   128
#define NSLICES 16
#define COLS_PER_SLICE (NROWS / NSLICES)   // 512
#define ROWS_PER_BLOCK 128                 // 4 waves x 2 row-tiles x 16
#define LDS_STRIDE 272                     // 256B row + 16B pad (conflict-free b128 reads)

typedef _Float16 v8h __attribute__((ext_vector_type(8)));
typedef _Float16 v2h __attribute__((ext_vector_type(2)));
typedef float    v4f __attribute__((ext_vector_type(4)));

#if __has_builtin(__builtin_amdgcn_exp2f)
#define EXP2F(x) __builtin_amdgcn_exp2f(x)
#else
#define EXP2F(x) exp2f(x)
#endif
#if __has_builtin(__builtin_amdgcn_logf)
#define LOG2F(x) __builtin_amdgcn_logf(x)
#else
#define LOG2F(x) __log2f(x)
#endif

// ---------------- Kernel 1: row-normalize concat(z_i, z_j) -> fp16 ----------------
// one wave per row; lane handles 2 columns; packed 4B store
__global__ __launch_bounds__(256) void nt_normalize(
        const float* __restrict__ z_i, const float* __restrict__ z_j,
        _Float16* __restrict__ zn) {
    int tid  = threadIdx.x;
    int lane = tid & 63;
    int row  = blockIdx.x * 4 + (tid >> 6);
    const float* src = (row < HALF) ? (z_i + (size_t)row * DDIM)
                                    : (z_j + (size_t)(row - HALF) * DDIM);
    float2 v = *(const float2*)(src + lane * 2);
    float ss = v.x * v.x + v.y * v.y;
    #pragma unroll
    for (int off = 32; off >= 1; off >>= 1)
        ss += __shfl_xor(ss, off, 64);
    float inv = 1.0f / fmaxf(sqrtf(ss), 1e-8f);
    v2h p;
    p.x = (_Float16)(v.x * inv);
    p.y = (_Float16)(v.y * inv);
    *(v2h*)(zn + (size_t)row * DDIM + lane * 2) = p;
}

// ---------------- Kernel 2: fused Gram (zn @ zn^T) + shifted sum-exp ----------------
// grid: 64 row-groups x 16 column slices. block: 256 thr = 4 waves.
// Each wave owns 32 rows (2 A-tiles held in registers). Per 64-col iteration:
// stage 64x128 f16 into padded LDS; each B fragment feeds 2 MFMAs (register
// blocking halves LDS read traffic vs R1). exp(2g-2) accumulated with the
// partner column masked; shift M=2 is a provable bound on all logits.
__global__ __launch_bounds__(256, 4) void nt_gram_lse(
        const _Float16* __restrict__ zn, float* __restrict__ S_part) {
    __shared__ unsigned char lds[64 * LDS_STRIDE];

    int tid  = threadIdx.x;
    int lane = tid & 63;
    int w    = tid >> 6;       // wave 0..3
    int quad = lane >> 4;      // 0..3
    int cl   = lane & 15;      // 0..15

    int rg    = blockIdx.x >> 4;        // 0..63
    int slice = blockIdx.x & 15;        // 0..15
    int r0    = rg * ROWS_PER_BLOCK;
    int c0    = slice * COLS_PER_SLICE;

    // A fragments: 2 row-tiles of 16 rows each, kept in registers all kernel.
    // A-operand layout: lane holds A[m = lane&15][k = quad*8 + j] (16B contiguous)
    v8h a[2][4];
    #pragma unroll
    for (int u = 0; u < 2; ++u) {
        int arow = r0 + u * 64 + w * 16 + cl;
        #pragma unroll
        for (int t = 0; t < 4; ++t)
            a[u][t] = *(const v8h*)(zn + (size_t)arow * DDIM + t * 32 + quad * 8);
    }

    // C/D layout: row = quad*4 + reg, col = lane&15
    int   orow[2][4], partner[2][4];
    float sums[2][4];
    #pragma unroll
    for (int u = 0; u < 2; ++u)
        #pragma unroll
        for (int r = 0; r < 4; ++r) {
            orow[u][r]    = r0 + u * 64 + w * 16 + quad * 4 + r;
            partner[u][r] = (orow[u][r] + HALF) & (NROWS - 1);
            sums[u][r]    = 0.f;
        }

    const uint4* gb = (const uint4*)zn;   // 1 uint4 = 8 f16
    const float C = 2.8853900817779268f;  // 2/ln2 ; exp(2g-2) = 2^(C*g - C)

    for (int it = 0; it < COLS_PER_SLICE / 64; ++it) {
        int ct = c0 + it * 64;
        // stage 64 cols x 128 K (16 KB), padded rows
        #pragma unroll
        for (int i = 0; i < 4; ++i) {
            uint4 v = gb[ct * 16 + i * 256 + tid];
            *(uint4*)&lds[(size_t)((tid >> 4) + i * 16) * LDS_STRIDE + (tid & 15) * 16] = v;
        }
        __syncthreads();

        #pragma unroll
        for (int sub = 0; sub < 4; ++sub) {
            v4f acc0 = {0.f, 0.f, 0.f, 0.f};
            v4f acc1 = {0.f, 0.f, 0.f, 0.f};
            #pragma unroll
            for (int t = 0; t < 4; ++t) {
                v8h b = *(const v8h*)&lds[(size_t)(sub * 16 + cl) * LDS_STRIDE + t * 64 + quad * 16];
                acc0 = __builtin_amdgcn_mfma_f32_16x16x32_f16(a[0][t], b, acc0, 0, 0, 0);
                acc1 = __builtin_amdgcn_mfma_f32_16x16x32_f16(a[1][t], b, acc1, 0, 0, 0);
            }
            int col = ct + sub * 16 + cl;
            #pragma unroll
            for (int r = 0; r < 4; ++r) {
                float e0 = EXP2F(fmaf(acc0[r], C, -C));
                float e1 = EXP2F(fmaf(acc1[r], C, -C));
                sums[0][r] += (col == partner[0][r]) ? 0.f : e0;
                sums[1][r] += (col == partner[1][r]) ? 0.f : e1;
            }
        }
        __syncthreads();
    }

    // reduce across the 16 column-lanes of each quad group
    #pragma unroll
    for (int u = 0; u < 2; ++u)
        #pragma unroll
        for (int r = 0; r < 4; ++r) {
            float s = sums[u][r];
            #pragma unroll
            for (int off = 1; off < 16; off <<= 1)
                s += __shfl_xor(s, off, 64);
            if (cl == 0)
                S_part[(size_t)slice * NROWS + orow[u][r]] = s;
        }
}

// ---------------- Kernel 3: loss = mean_r log(sum_slices S_part) ----------------
__global__ __launch_bounds__(256) void nt_finalize(
        const float* __restrict__ S_part, float* __restrict__ out) {
    __shared__ float red[4];
    int tid = threadIdx.x;
    float acc = 0.f;
    for (int r = tid; r < NROWS; r += 256) {
        float s = 0.f;
        #pragma unroll
        for (int sl = 0; sl < NSLICES; ++sl)
            s += S_part[(size_t)sl * NROWS + r];
        acc += LOG2F(s);
    }
    #pragma unroll
    for (int off = 32; off >= 1; off >>= 1)
        acc += __shfl_xor(acc, off, 64);
    if ((tid & 63) == 0) red[tid >> 6] = acc;
    __syncthreads();
    if (tid == 0) {
        float t = red[0] + red[1] + red[2] + red[3];
        out[0] = t * (0.69314718055994531f / (float)NROWS);
    }
}

extern "C" void kernel_launch(void* const* d_in, const int* in_sizes, int n_in,
                              void* d_out, int out_size, void* d_ws, size_t ws_size,
                              hipStream_t stream) {
    const float* z_i = (const float*)d_in[0];
    const float* z_j = (const float*)d_in[1];
    _Float16* zn     = (_Float16*)d_ws;                                   // 2 MB
    float*    S_part = (float*)((char*)d_ws + (size_t)NROWS * DDIM * 2);  // 16*8192 fp32
    float*    out    = (float*)d_out;

    nt_normalize<<<dim3(NROWS / 4), dim3(256), 0, stream>>>(z_i, z_j, zn);
    nt_gram_lse<<<dim3((NROWS / ROWS_PER_BLOCK) * NSLICES), dim3(256), 0, stream>>>(zn, S_part);
    nt_finalize<<<dim3(1), dim3(256), 0, stream>>>(S_part, out);
}

// Round 3
// 103.367 us; speedup vs baseline: 1.0878x; 1.0463x over previous
//
#include <hip/hip_runtime.h>

#define HALF   4096
#define NROWS  8192
#define DDIM   128
#define NGROUPS (NROWS / 128)              // 64 row/col groups of 128
#define NPAIRS  (NGROUPS * (NGROUPS + 1) / 2)  // 2080 triangular tile-blocks
#define LDS_STRIDE 272                     // 256B row + 16B pad (conflict-free b128)

typedef _Float16 v8h __attribute__((ext_vector_type(8)));
typedef _Float16 v2h __attribute__((ext_vector_type(2)));
typedef float    v4f __attribute__((ext_vector_type(4)));

#if __has_builtin(__builtin_amdgcn_exp2f)
#define EXP2F(x) __builtin_amdgcn_exp2f(x)
#else
#define EXP2F(x) exp2f(x)
#endif
#if __has_builtin(__builtin_amdgcn_logf)
#define LOG2F(x) __builtin_amdgcn_logf(x)
#else
#define LOG2F(x) __log2f(x)
#endif

#define CEXP 2.8853900817779268f   // 2/ln2 : exp(2g-2) = 2^(CEXP*g - CEXP)

// ---------------- Kernel 1: row-normalize concat(z_i, z_j) -> fp16; zero S/acc ----
__global__ __launch_bounds__(256) void nt_normalize(
        const float* __restrict__ z_i, const float* __restrict__ z_j,
        _Float16* __restrict__ zn, float* __restrict__ S, float* __restrict__ acc) {
    int tid  = threadIdx.x;
    int lane = tid & 63;
    int row  = blockIdx.x * 4 + (tid >> 6);
    // zero the accumulators the later kernels atomicAdd into (ws is 0xAA-poisoned)
    if (tid < 4) S[blockIdx.x * 4 + tid] = 0.f;
    if (blockIdx.x == 0 && tid == 4) acc[0] = 0.f;

    const float* src = (row < HALF) ? (z_i + (size_t)row * DDIM)
                                    : (z_j + (size_t)(row - HALF) * DDIM);
    float2 v = *(const float2*)(src + lane * 2);
    float ss = v.x * v.x + v.y * v.y;
    #pragma unroll
    for (int off = 32; off >= 1; off >>= 1)
        ss += __shfl_xor(ss, off, 64);
    float inv = 1.0f / fmaxf(sqrtf(ss), 1e-8f);
    v2h p;
    p.x = (_Float16)(v.x * inv);
    p.y = (_Float16)(v.y * inv);
    *(v2h*)(zn + (size_t)row * DDIM + lane * 2) = p;
}

// ---------------- Kernel 2: symmetric Gram + shifted sum-exp, triangular tiles ----
// 2080 blocks = upper-triangle (I<=J) of 64x64 grid of 128x128 tiles.
// exp(sim) is symmetric: each off-diagonal tile contributes its row-sums to
// S[rows of I] AND its column-sums to S[cols of J] — halves MFMA/LDS/exp work.
// Partner-column exclusion is deferred to nt_correct (removes cndmask from the
// hot loop). Shift M=2 >= all logits, so partial sum-exps add directly.
__global__ __launch_bounds__(256, 4) void nt_gram_sym(
        const _Float16* __restrict__ zn, float* __restrict__ S) {
    __shared__ unsigned char lds[128 * LDS_STRIDE];   // 34816 B

    int tid  = threadIdx.x;
    int lane = tid & 63;
    int w    = tid >> 6;       // wave 0..3
    int quad = lane >> 4;      // 0..3
    int cl   = lane & 15;      // 0..15

    // decode triangular pair index -> (I, J), I <= J
    int p = blockIdx.x;
    int J = (int)((sqrtf(8.0f * (float)p + 1.0f) - 1.0f) * 0.5f);
    while ((J + 1) * (J + 2) / 2 <= p) ++J;
    while (J * (J + 1) / 2 > p) --J;
    int I = p - J * (J + 1) / 2;
    int r0 = I * 128, c0 = J * 128;
    bool offdiag = (I != J);

    // A fragments: wave w owns 32 rows (2 tiles of 16), kept in registers.
    // A-operand layout: lane holds A[m = lane&15][k = quad*8 + j]
    v8h a[2][4];
    #pragma unroll
    for (int u = 0; u < 2; ++u) {
        int arow = r0 + w * 32 + u * 16 + cl;
        #pragma unroll
        for (int t = 0; t < 4; ++t)
            a[u][t] = *(const v8h*)(zn + (size_t)arow * DDIM + t * 32 + quad * 8);
    }

    // stage the 128-column tile (128 x 128 f16 = 32 KB) once, padded rows
    const uint4* gb = (const uint4*)zn;   // 1 uint4 = 8 f16
    #pragma unroll
    for (int i = 0; i < 8; ++i) {
        int rr = (tid >> 4) + i * 16;     // 0..127 (column index within tile)
        uint4 v = gb[(size_t)(c0 + rr) * 16 + (tid & 15)];
        *(uint4*)&lds[(size_t)rr * LDS_STRIDE + (tid & 15) * 16] = v;
    }
    __syncthreads();

    float sums[2][4] = {{0.f,0.f,0.f,0.f},{0.f,0.f,0.f,0.f}};

    #pragma unroll
    for (int sub = 0; sub < 8; ++sub) {
        v4f acc0 = {0.f, 0.f, 0.f, 0.f};
        v4f acc1 = {0.f, 0.f, 0.f, 0.f};
        #pragma unroll
        for (int t = 0; t < 4; ++t) {
            v8h b = *(const v8h*)&lds[(size_t)(sub * 16 + cl) * LDS_STRIDE + t * 64 + quad * 16];
            acc0 = __builtin_amdgcn_mfma_f32_16x16x32_f16(a[0][t], b, acc0, 0, 0, 0);
            acc1 = __builtin_amdgcn_mfma_f32_16x16x32_f16(a[1][t], b, acc1, 0, 0, 0);
        }
        // epilogue: exp(2g-2); accumulate row sums in regs, column sums cross-lane
        float cp = 0.f;
        #pragma unroll
        for (int r = 0; r < 4; ++r) {
            float e0 = EXP2F(fmaf(acc0[r], CEXP, -CEXP));
            float e1 = EXP2F(fmaf(acc1[r], CEXP, -CEXP));
            sums[0][r] += e0;
            sums[1][r] += e1;
            cp += e0 + e1;
        }
        if (offdiag) {
            // column sums: reduce over the wave's 32 rows (across quads)
            cp += __shfl_xor(cp, 16, 64);
            cp += __shfl_xor(cp, 32, 64);
            if (quad == 0)
                atomicAdd(&S[c0 + sub * 16 + cl], cp);
        }
    }

    // row sums: reduce across the 16 column-lanes, one atomic per row
    #pragma unroll
    for (int u = 0; u < 2; ++u)
        #pragma unroll
        for (int r = 0; r < 4; ++r) {
            float s = sums[u][r];
            #pragma unroll
            for (int off = 1; off < 16; off <<= 1)
                s += __shfl_xor(s, off, 64);
            if (cl == 0)
                atomicAdd(&S[r0 + w * 32 + u * 16 + quad * 4 + r], s);
        }
}

// ---------------- Kernel 3: subtract partner term, log, reduce ----------------
// one wave per row-pair (r, r+HALF): recompute dot(zn[r], zn[r+HALF]) in fp32
// (matches the MFMA value to ~1e-6), subtract its exp from both rows' sums,
// take log2, block-reduce, atomicAdd into acc.
__global__ __launch_bounds__(256) void nt_correct(
        const _Float16* __restrict__ zn, const float* __restrict__ S,
        float* __restrict__ acc) {
    int tid  = threadIdx.x;
    int lane = tid & 63;
    int w    = tid >> 6;
    int pr   = blockIdx.x * 4 + w;   // pair 0..4095

    v2h xa = *(const v2h*)(zn + (size_t)pr * DDIM + lane * 2);
    v2h xb = *(const v2h*)(zn + (size_t)(pr + HALF) * DDIM + lane * 2);
    float d = (float)xa.x * (float)xb.x + (float)xa.y * (float)xb.y;
    #pragma unroll
    for (int off = 32; off >= 1; off >>= 1)
        d += __shfl_xor(d, off, 64);

    __shared__ float red[4];
    if (lane == 0) {
        float e = EXP2F(fmaf(d, CEXP, -CEXP));
        red[w] = LOG2F(S[pr] - e) + LOG2F(S[pr + HALF] - e);
    }
    __syncthreads();
    if (tid == 0)
        atomicAdd(acc, red[0] + red[1] + red[2] + red[3]);
}

// ---------------- Kernel 4: final scale ----------------
__global__ void nt_final(const float* __restrict__ acc, float* __restrict__ out) {
    out[0] = acc[0] * (0.69314718055994531f / (float)NROWS);
}

extern "C" void kernel_launch(void* const* d_in, const int* in_sizes, int n_in,
                              void* d_out, int out_size, void* d_ws, size_t ws_size,
                              hipStream_t stream) {
    const float* z_i = (const float*)d_in[0];
    const float* z_j = (const float*)d_in[1];
    _Float16* zn = (_Float16*)d_ws;                                     // 2 MB
    float*    S  = (float*)((char*)d_ws + (size_t)NROWS * DDIM * 2);    // 8192 f32
    float*    acc = S + NROWS;                                          // 1 f32
    float*    out = (float*)d_out;

    nt_normalize<<<dim3(NROWS / 4), dim3(256), 0, stream>>>(z_i, z_j, zn, S, acc);
    nt_gram_sym<<<dim3(NPAIRS), dim3(256), 0, stream>>>(zn, S);
    nt_correct<<<dim3(HALF / 4), dim3(256), 0, stream>>>(zn, S, acc);
    nt_final<<<dim3(1), dim3(1), 0, stream>>>(acc, out);
}